// Round 10
// baseline (379.040 us; speedup 1.0000x reference)
//
#include <hip/hip_runtime.h>
#include <math.h>

#define PI_F 3.14159265358979323846f

// ---------------------------------------------------------------------------
// GF(2) deferred-CNOT bookkeeping + 6-gate fusion, ALL at compile time.
// CNOTs are index relabelings tracked in M / M^-1; Rot on logical wire w pairs
// p <-> p^col[w], role = parity(p & row[w]); within a layer
// parity(col[j] & row[i]) = delta_ij. Layer 0 Rots fold into the init.
//
// R10: 6 gates per pass (2 passes/layer, 10 total). Per thread: 16 amps in
// registers (levels 0-3, masks m0..m3, gray-chain LDS) + 2 cross-lane levels:
// t bit0 <-> m4 (partner lane^1, DPP quad_perm 0xB1), t bit1 <-> m5 (lane^2,
// 0x4E). Representative q is built from {m4, m5, nb0..nb5} where nb spans the
// null space of all 6 roles -> all in-register levels use raw coefficients;
// cross-level side = t&1 / t&2 exactly.
// ---------------------------------------------------------------------------
struct Tab {
    unsigned gmask[10][4];   // in-register pairing masks m0..m3
    int      ggate[10][6];   // gate idx (layer*12+wire); lev 0-3 reg, 4-5 cross
    unsigned m45[10][2];     // cross masks m4 (t bit0), m5 (t bit1)
    unsigned nb[10][6];      // null basis for t bits 2..7
    unsigned zrow[12];       // final measurement parity rows
};

constexpr int rank4_low4(unsigned a, unsigned b, unsigned c, unsigned d) {
    unsigned v[4] = { a & 15u, b & 15u, c & 15u, d & 15u };
    int rank = 0;
    for (int col = 0; col < 4; ++col) {
        int sel = -1;
        for (int i = rank; i < 4; ++i) if ((v[i] >> col) & 1u) { sel = i; break; }
        if (sel < 0) continue;
        unsigned tmp = v[rank]; v[rank] = v[sel]; v[sel] = tmp;
        for (int i = 0; i < 4; ++i)
            if (i != rank && ((v[i] >> col) & 1u)) v[i] ^= v[rank];
        ++rank;
    }
    return rank;
}

constexpr Tab make_tab() {
    Tab tb{};
    unsigned col[12] = {}, row[12] = {};
    for (int w = 0; w < 12; ++w) { col[w] = 1u << (11 - w); row[w] = 1u << (11 - w); }
    // layer 0: Rots folded into init; apply its CNOTs (r = 1)
    for (int w = 0; w < 12; ++w) {
        const int c = w, tg = (w + 1) % 12;
        col[c] ^= col[tg];
        row[tg] ^= row[c];
    }
    int pass = 0;
    for (int l = 1; l < 6; ++l) {
        for (int grp = 0; grp < 2; ++grp) {
            int gw[6] = {};
            unsigned gm[6] = {}, gr[6] = {};
            for (int i = 0; i < 6; ++i) {
                gw[i] = grp * 6 + i;
                gm[i] = col[gw[i]];
                gr[i] = row[gw[i]];
            }
            // ---- null space of the 6 roles (prefer high pivot cols) --------
            unsigned R[6] = {};
            for (int i = 0; i < 6; ++i) R[i] = gr[i];
            int pivc[6] = { -1,-1,-1,-1,-1,-1 };
            bool ispiv[12] = {};
            int rr = 0;
            for (int cc = 11; cc >= 0 && rr < 6; --cc) {
                int sel = -1;
                for (int i = rr; i < 6; ++i) if ((R[i] >> cc) & 1u) { sel = i; break; }
                if (sel < 0) continue;
                unsigned tmp = R[rr]; R[rr] = R[sel]; R[sel] = tmp;
                for (int i = 0; i < 6; ++i)
                    if (i != rr && ((R[i] >> cc) & 1u)) R[i] ^= R[rr];
                pivc[rr] = cc; ispiv[cc] = true; ++rr;
            }
            unsigned nbv[6] = {};
            int nn = 0;
            for (int cc = 0; cc < 12; ++cc) {
                if (ispiv[cc]) continue;
                unsigned v = 1u << cc;
                for (int i = 0; i < rr; ++i)
                    if ((R[i] >> cc) & 1u) v |= 1u << pivc[i];
                nbv[nn++] = v;
            }
            // ---- RREF over low-4 cols; aligned pivots first ----------------
            unsigned vv[6] = {};
            for (int i = 0; i < 6; ++i) vv[i] = nbv[i];
            int pr[4] = { -1,-1,-1,-1 };
            int ri = 0;
            for (int cc = 0; cc < 4; ++cc) {
                int sel = -1;
                for (int i = ri; i < 6; ++i) if ((vv[i] >> cc) & 1u) { sel = i; break; }
                if (sel < 0) continue;
                unsigned tmp = vv[ri]; vv[ri] = vv[sel]; vv[sel] = tmp;
                for (int i = 0; i < 6; ++i)
                    if (i != ri && ((vv[i] >> cc) & 1u)) vv[i] ^= vv[ri];
                pr[cc] = ri; ++ri;
            }
            unsigned nbf[6] = {};
            bool used[6] = {};
            int ns = 0;
            for (int cc = 0; cc < 4; ++cc)
                if (pr[cc] >= 0) { nbf[ns++] = vv[pr[cc]]; used[pr[cc]] = true; }
            for (int i = 0; i < 6; ++i)
                if (!used[i]) nbf[ns++] = vv[i];
            // ---- pick cross pair maximizing low-4 bank coverage ------------
            int best = -1, ba = 4, bb = 5;
            for (int a = 0; a < 6; ++a)
                for (int b2 = a + 1; b2 < 6; ++b2) {
                    const int rk = rank4_low4(gm[a], gm[b2], nbf[0], nbf[1]);
                    if (rk > best) { best = rk; ba = a; bb = b2; }
                }
            int nr = 0;
            for (int i = 0; i < 6; ++i) {
                if (i == ba || i == bb) continue;
                tb.gmask[pass][nr] = gm[i];
                tb.ggate[pass][nr] = l * 12 + gw[i];
                ++nr;
            }
            tb.ggate[pass][4] = l * 12 + gw[ba];
            tb.ggate[pass][5] = l * 12 + gw[bb];
            tb.m45[pass][0] = gm[ba];
            tb.m45[pass][1] = gm[bb];
            for (int i = 0; i < 6; ++i) tb.nb[pass][i] = nbf[i];
            ++pass;
        }
        const int r = l + 1;
        for (int w = 0; w < 12; ++w) {
            const int c = w, tg = (w + r) % 12;
            col[c] ^= col[tg];
            row[tg] ^= row[c];
        }
    }
    for (int w = 0; w < 12; ++w) tb.zrow[w] = row[w];
    return tb;
}

__constant__ Tab GT = make_tab();

// pass-ordered Rot coefs: [pass*48 + lev*8 + j] for 10 passes (lev 0..5);
// layer-0 gates (folded into init) at [480 + w*8 + j].
__device__ float g_coef[576];

__device__ __forceinline__ void rot8(const float* __restrict__ wp, float* o) {
    const float phi = wp[0], th = wp[1], om = wp[2];
    const float hs = 0.5f * (phi + om), hd = 0.5f * (phi - om), ht = 0.5f * th;
    const float ctt = cosf(ht), stt = sinf(ht);
    const float cs = cosf(hs), ss = sinf(hs);
    const float cd = cosf(hd), sd = sinf(hd);
    o[0] = cs * ctt;  o[1] = -ss * ctt;   // u00
    o[2] = -cd * stt; o[3] = -sd * stt;   // u01
    o[4] = cd * stt;  o[5] = -sd * stt;   // u10
    o[6] = cs * ctt;  o[7] = ss * ctt;    // u11
}

__global__ void rot_coef_kernel(const float* __restrict__ weights) {
    const int i = blockIdx.x * blockDim.x + threadIdx.x;
    if (i < 60) {
        const int ps = i / 6, lev = i % 6;
        const int g = GT.ggate[ps][lev];
        float o[8];
        rot8(weights + g * 3, o);
        #pragma unroll
        for (int j = 0; j < 8; ++j) g_coef[ps * 48 + lev * 8 + j] = o[j];
    } else if (i >= 64 && i < 76) {
        const int w = i - 64;
        float o[8];
        rot8(weights + w * 3, o);
        #pragma unroll
        for (int j = 0; j < 8; ++j) g_coef[480 + w * 8 + j] = o[j];
    }
}

__device__ __forceinline__ float2 cmul(float2 A, float2 B) {
    return make_float2(A.x * B.x - A.y * B.y, A.x * B.y + A.y * B.x);
}

// one 2x2 complex butterfly on two NAMED register operands
__device__ __forceinline__ void bf(float2& X, float2& Y,
                                   float Ar, float Ai, float Br, float Bi,
                                   float Cr, float Ci, float Dr, float Di) {
    const float2 x = X, y = Y;
    X.x = Ar * x.x - Ai * x.y + Br * y.x - Bi * y.y;
    X.y = Ar * x.y + Ai * x.x + Br * y.y + Bi * y.x;
    Y.x = Cr * x.x - Ci * x.y + Dr * y.x - Di * y.y;
    Y.y = Cr * x.y + Ci * x.x + Dr * y.y + Di * y.x;
}

// cross-lane fetch via DPP quad_perm (VALU pipe, no LDS traffic)
template <int CTRL>
__device__ __forceinline__ float dpp_f(float x) {
    return __int_as_float(
        __builtin_amdgcn_mov_dpp(__float_as_int(x), CTRL, 0xF, 0xF, true));
}

// ---------------------------------------------------------------------------
// One block (256 threads) per batch element. LDS = exactly the 32 KB state.
// 10 fused passes (6 gates each): 4 in-register levels (gray-chain LDS) +
// 2 DPP cross-lane levels. Named registers + opaque asm (R5/R7 lessons).
// ---------------------------------------------------------------------------
__global__ __launch_bounds__(256) void qvl_fused(
    const float* __restrict__ v,        // (B, 512)
    const float* __restrict__ Wc,       // (12, 512)
    const float* __restrict__ bc,       // (12,)
    float* __restrict__ out)            // (B, 12)
{
    __shared__ float2 st[4096];     // 32768 B total LDS
    float* redf = reinterpret_cast<float*>(st);   // overlay (48 floats)

    const int t    = threadIdx.x;
    const int lane = t & 63;
    const int wv   = t >> 6;
    const int b    = blockIdx.x;

    // ---- x_w = tanh(v[b] . Wc[w] + bc[w]) * pi (partials into overlay) -----
    {
        const float2 vv = reinterpret_cast<const float2*>(v + b * 512)[t];
        #pragma unroll
        for (int w = 0; w < 12; ++w) {
            const float2 ww = reinterpret_cast<const float2*>(Wc + w * 512)[t];
            float p = vv.x * ww.x + vv.y * ww.y;
            #pragma unroll
            for (int s = 1; s < 64; s <<= 1) p += __shfl_xor(p, s, 64);
            if (lane == 0) redf[w * 4 + wv] = p;
        }
    }
    __syncthreads();

    // ---- per-wave: lanes 0..11 fold RY(x_w) + layer-0 Rot into (aw, bw) ----
    float2 aw = make_float2(0.0f, 0.0f), bw = aw;
    if (lane < 12) {
        const float x = tanhf(redf[lane * 4 + 0] + redf[lane * 4 + 1] +
                              redf[lane * 4 + 2] + redf[lane * 4 + 3] + bc[lane]) * PI_F;
        const float h = 0.5f * x;
        const float c = cosf(h), s = sinf(h);
        const float* c8 = g_coef + 480 + lane * 8;
        aw = make_float2(c8[0] * c + c8[2] * s, c8[1] * c + c8[3] * s);
        bw = make_float2(c8[4] * c + c8[6] * s, c8[5] * c + c8[7] * s);
    }
    __syncthreads();   // overlay reads done before init overwrites st

    // ---- init: product state; p = k*256 + t (t bits -> wires 11..4) --------
    {
        float2 hi = make_float2(1.0f, 0.0f);
        #pragma unroll
        for (int j = 0; j < 8; ++j) {
            const int src = 11 - j;            // wire for p bit j
            const float ax = __shfl(aw.x, src, 64), ay = __shfl(aw.y, src, 64);
            const float bx = __shfl(bw.x, src, 64), by = __shfl(bw.y, src, 64);
            const int bit = (t >> j) & 1;
            hi = cmul(hi, make_float2(bit ? bx : ax, bit ? by : ay));
        }
        float2 A3 = make_float2(__shfl(aw.x, 3, 64), __shfl(aw.y, 3, 64));
        float2 B3 = make_float2(__shfl(bw.x, 3, 64), __shfl(bw.y, 3, 64));
        float2 A2 = make_float2(__shfl(aw.x, 2, 64), __shfl(aw.y, 2, 64));
        float2 B2 = make_float2(__shfl(bw.x, 2, 64), __shfl(bw.y, 2, 64));
        float2 A1 = make_float2(__shfl(aw.x, 1, 64), __shfl(aw.y, 1, 64));
        float2 B1 = make_float2(__shfl(bw.x, 1, 64), __shfl(bw.y, 1, 64));
        float2 A0 = make_float2(__shfl(aw.x, 0, 64), __shfl(aw.y, 0, 64));
        float2 B0 = make_float2(__shfl(bw.x, 0, 64), __shfl(bw.y, 0, 64));
        float2 fA[4], fB[4];
        #pragma unroll
        for (int m = 0; m < 4; ++m) {
            fA[m] = cmul((m & 1) ? B3 : A3, (m & 2) ? B2 : A2);   // p bits 8,9
            fB[m] = cmul((m & 1) ? B1 : A1, (m & 2) ? B0 : A0);   // p bits 10,11
        }
        #pragma unroll
        for (int k = 0; k < 16; ++k)
            st[k * 256 + t] = cmul(hi, cmul(fA[k & 3], fB[k >> 2]));
    }

    // ---- 10 fused passes (layers 1..5, 6 gates each) ------------------------
    #pragma unroll 1
    for (int ps = 0; ps < 10; ++ps) {
        __syncthreads();
        const float* cp = g_coef + ps * 48;    // uniform -> s_load
        const unsigned m0 = GT.gmask[ps][0], m1 = GT.gmask[ps][1];
        const unsigned m2 = GT.gmask[ps][2], m3 = GT.gmask[ps][3];
        // representative: t bit0 -> m4, bit1 -> m5, bits 2..7 -> null basis
        unsigned q = 0u;
        q ^= (t & 1)   ? GT.m45[ps][0] : 0u;
        q ^= (t & 2)   ? GT.m45[ps][1] : 0u;
        q ^= (t & 4)   ? GT.nb[ps][0] : 0u;
        q ^= (t & 8)   ? GT.nb[ps][1] : 0u;
        q ^= (t & 16)  ? GT.nb[ps][2] : 0u;
        q ^= (t & 32)  ? GT.nb[ps][3] : 0u;
        q ^= (t & 64)  ? GT.nb[ps][4] : 0u;
        q ^= (t & 128) ? GT.nb[ps][5] : 0u;

        // Gray-code load chain (one rolling address register)
        unsigned ad = q;
        float2 g0  = st[ad]; ad ^= m0;
        float2 g1  = st[ad]; ad ^= m1;
        float2 g3  = st[ad]; ad ^= m0;
        float2 g2  = st[ad]; ad ^= m2;
        float2 g6  = st[ad]; ad ^= m0;
        float2 g7  = st[ad]; ad ^= m1;
        float2 g5  = st[ad]; ad ^= m0;
        float2 g4  = st[ad]; ad ^= m3;
        float2 g12 = st[ad]; ad ^= m0;
        float2 g13 = st[ad]; ad ^= m1;
        float2 g15 = st[ad]; ad ^= m0;
        float2 g14 = st[ad]; ad ^= m2;
        float2 g10 = st[ad]; ad ^= m0;
        float2 g11 = st[ad]; ad ^= m1;
        float2 g9  = st[ad]; ad ^= m0;
        float2 g8  = st[ad];

        // ---- 4 in-register levels: raw coefs (parity-0 representatives) ----
        #define BF(X, Y) bf(X, Y, Ar, Ai, Br, Bi, Cr, Ci, Dr, Di)
        { const float Ar = cp[0],  Ai = cp[1],  Br = cp[2],  Bi = cp[3];
          const float Cr = cp[4],  Ci = cp[5],  Dr = cp[6],  Di = cp[7];
          BF(g0,g1); BF(g2,g3); BF(g4,g5); BF(g6,g7);
          BF(g8,g9); BF(g10,g11); BF(g12,g13); BF(g14,g15); }
        { const float Ar = cp[8],  Ai = cp[9],  Br = cp[10], Bi = cp[11];
          const float Cr = cp[12], Ci = cp[13], Dr = cp[14], Di = cp[15];
          BF(g0,g2); BF(g1,g3); BF(g4,g6); BF(g5,g7);
          BF(g8,g10); BF(g9,g11); BF(g12,g14); BF(g13,g15); }
        { const float Ar = cp[16], Ai = cp[17], Br = cp[18], Bi = cp[19];
          const float Cr = cp[20], Ci = cp[21], Dr = cp[22], Di = cp[23];
          BF(g0,g4); BF(g1,g5); BF(g2,g6); BF(g3,g7);
          BF(g8,g12); BF(g9,g13); BF(g10,g14); BF(g11,g15); }
        { const float Ar = cp[24], Ai = cp[25], Br = cp[26], Bi = cp[27];
          const float Cr = cp[28], Ci = cp[29], Dr = cp[30], Di = cp[31];
          BF(g0,g8); BF(g1,g9); BF(g2,g10); BF(g3,g11);
          BF(g4,g12); BF(g5,g13); BF(g6,g14); BF(g7,g15); }
        #undef BF

        // ---- cross level 4: partner = lane^1 (quad_perm 0xB1), side = t&1 --
        {
            const bool s_ = (t & 1) != 0;
            const float Pr = s_ ? cp[38] : cp[32];
            const float Pi = s_ ? cp[39] : cp[33];
            const float Qr = s_ ? cp[36] : cp[34];
            const float Qi = s_ ? cp[37] : cp[35];
            #define XAMP(G) { const float ox = dpp_f<0xB1>(G.x), oy = dpp_f<0xB1>(G.y); \
                const float nx = Pr*G.x - Pi*G.y + Qr*ox - Qi*oy;                        \
                const float ny = Pr*G.y + Pi*G.x + Qr*oy + Qi*ox;                        \
                G.x = nx; G.y = ny; }
            XAMP(g0) XAMP(g1) XAMP(g2) XAMP(g3) XAMP(g4) XAMP(g5) XAMP(g6) XAMP(g7)
            XAMP(g8) XAMP(g9) XAMP(g10) XAMP(g11) XAMP(g12) XAMP(g13) XAMP(g14) XAMP(g15)
            #undef XAMP
        }
        // ---- cross level 5: partner = lane^2 (quad_perm 0x4E), side = t&2 --
        {
            const bool s_ = (t & 2) != 0;
            const float Pr = s_ ? cp[46] : cp[40];
            const float Pi = s_ ? cp[47] : cp[41];
            const float Qr = s_ ? cp[44] : cp[42];
            const float Qi = s_ ? cp[45] : cp[43];
            #define XAMP(G) { const float ox = dpp_f<0x4E>(G.x), oy = dpp_f<0x4E>(G.y); \
                const float nx = Pr*G.x - Pi*G.y + Qr*ox - Qi*oy;                        \
                const float ny = Pr*G.y + Pi*G.x + Qr*oy + Qi*ox;                        \
                G.x = nx; G.y = ny; }
            XAMP(g0) XAMP(g1) XAMP(g2) XAMP(g3) XAMP(g4) XAMP(g5) XAMP(g6) XAMP(g7)
            XAMP(g8) XAMP(g9) XAMP(g10) XAMP(g11) XAMP(g12) XAMP(g13) XAMP(g14) XAMP(g15)
            #undef XAMP
        }

        // opaque barrier on q: store chain recomputed, not CSE'd with loads
        asm volatile("" : "+v"(q));

        ad = q;
        st[ad] = g0;  ad ^= m0;
        st[ad] = g1;  ad ^= m1;
        st[ad] = g3;  ad ^= m0;
        st[ad] = g2;  ad ^= m2;
        st[ad] = g6;  ad ^= m0;
        st[ad] = g7;  ad ^= m1;
        st[ad] = g5;  ad ^= m0;
        st[ad] = g4;  ad ^= m3;
        st[ad] = g12; ad ^= m0;
        st[ad] = g13; ad ^= m1;
        st[ad] = g15; ad ^= m0;
        st[ad] = g14; ad ^= m2;
        st[ad] = g10; ad ^= m0;
        st[ad] = g11; ad ^= m1;
        st[ad] = g9;  ad ^= m0;
        st[ad] = g8;
    }
    __syncthreads();

    // ---- PauliZ expvals; p = k*256 + t, sign = parity(p & zrow) ------------
    float p2[16];
    #pragma unroll
    for (int k = 0; k < 16; ++k) {
        const float2 aa = st[k * 256 + t];
        p2[k] = aa.x * aa.x + aa.y * aa.y;
    }
    __syncthreads();   // all st reads done before overlay reuse
    #pragma unroll
    for (int w = 0; w < 12; ++w) {
        const unsigned zr = GT.zrow[w];
        const unsigned Aw = (unsigned)__popc((unsigned)t & zr) & 1u;
        const unsigned nm = (zr >> 8) & 0xFu;
        unsigned P = 0u;
        P ^= (nm & 1u) ? 0xAAAAu : 0u;
        P ^= (nm & 2u) ? 0xCCCCu : 0u;
        P ^= (nm & 4u) ? 0xF0F0u : 0u;
        P ^= (nm & 8u) ? 0xFF00u : 0u;
        P ^= Aw ? 0xFFFFu : 0u;
        float z = 0.0f;
        #pragma unroll
        for (int k = 0; k < 16; ++k)
            z += ((P >> k) & 1u) ? -p2[k] : p2[k];
        #pragma unroll
        for (int s = 1; s < 64; s <<= 1) z += __shfl_xor(z, s, 64);
        if (lane == 0) redf[w * 4 + wv] = z;
    }
    __syncthreads();
    if (t < 12)
        out[b * 12 + t] = redf[t * 4 + 0] + redf[t * 4 + 1] +
                          redf[t * 4 + 2] + redf[t * 4 + 3];
}

extern "C" void kernel_launch(void* const* d_in, const int* in_sizes, int n_in,
                              void* d_out, int out_size, void* d_ws, size_t ws_size,
                              hipStream_t stream) {
    (void)n_in; (void)out_size; (void)d_ws; (void)ws_size;
    const float* v   = (const float*)d_in[0];
    const float* Wc  = (const float*)d_in[1];
    const float* bc  = (const float*)d_in[2];
    const float* wts = (const float*)d_in[3];
    float* out = (float*)d_out;

    const int B = in_sizes[0] / 512;
    rot_coef_kernel<<<1, 128, 0, stream>>>(wts);
    qvl_fused<<<B, 256, 0, stream>>>(v, Wc, bc, out);
}

// Round 11
// 261.414 us; speedup vs baseline: 1.4500x; 1.4500x over previous
//
#include <hip/hip_runtime.h>
#include <math.h>

#define PI_F 3.14159265358979323846f

typedef float v2f __attribute__((ext_vector_type(2)));

// ---------------------------------------------------------------------------
// GF(2) deferred-CNOT bookkeeping + 4-gate fusion, ALL at compile time.
// CNOTs are index relabelings tracked in M / M^-1; Rot on logical wire w pairs
// p <-> p^col[w], role = parity(p & row[w]); within a layer
// parity(col[j] & row[i]) = delta_ij, so 4 gates tile the state into 256
// cosets of 16 amps. Layer 0 Rots fold into the product-state init.
// Coset representative chosen in the NULL SPACE of the 4 role rows ->
// raw coefficients, no per-thread role selection (R9).
// ---------------------------------------------------------------------------
struct Tab {
    unsigned gmask[15][4];   // pairing masks per pass
    unsigned grole[15][4];   // role parity rows per pass
    int      ggate[15][4];   // gate index (layer*12 + wire) for coef writer
    unsigned nb[15][8];      // null-space basis; q = XOR_{i: t bit i} nb[i]
    unsigned zrow[12];       // final measurement parity rows
};

constexpr Tab make_tab() {
    Tab tb{};
    unsigned col[12] = {}, row[12] = {};
    for (int w = 0; w < 12; ++w) { col[w] = 1u << (11 - w); row[w] = 1u << (11 - w); }
    // layer 0: Rots folded into init; apply its CNOTs (r = 1)
    for (int w = 0; w < 12; ++w) {
        const int c = w, tg = (w + 1) % 12;
        col[c] ^= col[tg];
        row[tg] ^= row[c];
    }
    int pass = 0;
    for (int l = 1; l < 6; ++l) {
        unsigned gm[3][4] = {}, gr[3][4] = {};
        int gg[3][4] = {};
        bool found = false;
        // multi-seed strict search on ROLE span: reject groups whose role-span
        // contains a nonzero low-4-only combo (keeps bank coverage).
        for (int seed = 0; seed < 12 && !found; ++seed) {
            bool used[12] = {};
            bool ok_all = true;
            unsigned tgm[3][4] = {}, tgr[3][4] = {};
            int tgg[3][4] = {};
            for (int grp = 0; grp < 3 && ok_all; ++grp) {
                int ns = 0;
                unsigned spanv[16] = {};
                int nspan = 1;
                for (int ww = 0; ww < 12 && ns < 4; ++ww) {
                    const int w = (ww + seed) % 12;
                    if (used[w]) continue;
                    bool ok = true;
                    for (int s2 = 0; s2 < nspan; ++s2) {
                        const unsigned comb = spanv[s2] ^ row[w];
                        if (comb != 0u && (comb & ~0xFu) == 0u) { ok = false; break; }
                    }
                    if (!ok) continue;
                    for (int s2 = 0; s2 < nspan; ++s2) spanv[nspan + s2] = spanv[s2] ^ row[w];
                    nspan *= 2;
                    used[w] = true;
                    tgm[grp][ns] = col[w]; tgr[grp][ns] = row[w]; tgg[grp][ns] = l * 12 + w;
                    ++ns;
                }
                if (ns < 4) ok_all = false;
            }
            if (ok_all) {
                for (int g2 = 0; g2 < 3; ++g2)
                    for (int i = 0; i < 4; ++i) {
                        gm[g2][i] = tgm[g2][i]; gr[g2][i] = tgr[g2][i]; gg[g2][i] = tgg[g2][i];
                    }
                found = true;
            }
        }
        if (!found) {
            bool used[12] = {};
            for (int grp = 0; grp < 3; ++grp) {
                int ns = 0;
                for (int w = 0; w < 12 && ns < 4; ++w) {
                    if (used[w]) continue;
                    used[w] = true;
                    gm[grp][ns] = col[w]; gr[grp][ns] = row[w]; gg[grp][ns] = l * 12 + w;
                    ++ns;
                }
            }
        }
        for (int grp = 0; grp < 3; ++grp) {
            for (int i = 0; i < 4; ++i) {
                tb.gmask[pass][i] = gm[grp][i];
                tb.grole[pass][i] = gr[grp][i];
                tb.ggate[pass][i] = gg[grp][i];
            }
            // ---- null-space basis of {p : parity(p & r_i) == 0, i=0..3} ----
            unsigned Rm[4] = { gr[grp][0], gr[grp][1], gr[grp][2], gr[grp][3] };
            int pivc[4] = { -1, -1, -1, -1 };
            int rr = 0;
            const int order[12] = { 11,10,9,8,7,6,5,4,3,2,1,0 };
            for (int ci = 0; ci < 12 && rr < 4; ++ci) {
                const int c = order[ci];
                int sel = -1;
                for (int i = rr; i < 4; ++i) if ((Rm[i] >> c) & 1u) { sel = i; break; }
                if (sel < 0) continue;
                unsigned tmp = Rm[rr]; Rm[rr] = Rm[sel]; Rm[sel] = tmp;
                for (int i = 0; i < 4; ++i)
                    if (i != rr && ((Rm[i] >> c) & 1u)) Rm[i] ^= Rm[rr];
                pivc[rr] = c; ++rr;
            }
            unsigned nbs[8] = {};
            int nn = 0;
            for (int c = 0; c < 12; ++c) {
                bool isp = false;
                for (int i = 0; i < 4; ++i) if (pivc[i] == c) isp = true;
                if (isp) continue;
                unsigned v2 = 1u << c;
                for (int i = 0; i < 4; ++i)
                    if ((Rm[i] >> c) & 1u) v2 |= 1u << pivc[i];
                nbs[nn++] = v2;
            }
            // align low4: RREF the 8 basis rows over columns 0..3
            unsigned vv[8] = {};
            for (int i = 0; i < 8; ++i) vv[i] = nbs[i];
            int pivr[4] = { -1, -1, -1, -1 };
            int rowi = 0;
            for (int c = 0; c < 4 && rowi < 8; ++c) {
                int sel = -1;
                for (int i = rowi; i < 8; ++i) if ((vv[i] >> c) & 1u) { sel = i; break; }
                if (sel < 0) continue;
                unsigned tmp = vv[rowi]; vv[rowi] = vv[sel]; vv[sel] = tmp;
                for (int i = 0; i < 8; ++i)
                    if (i != rowi && ((vv[i] >> c) & 1u)) vv[i] ^= vv[rowi];
                pivr[c] = rowi; ++rowi;
            }
            unsigned fin[8] = {};
            bool rowused[8] = {};
            bool slot[8] = {};
            for (int j = 0; j < 4; ++j)
                if (pivr[j] >= 0) { fin[j] = vv[pivr[j]]; rowused[pivr[j]] = true; slot[j] = true; }
            int fs = 0;
            for (int i = 0; i < 8; ++i) {
                if (rowused[i]) continue;
                while (fs < 8 && slot[fs]) ++fs;
                fin[fs] = vv[i]; slot[fs] = true; ++fs;
            }
            for (int i = 0; i < 8; ++i) tb.nb[pass][i] = fin[i];
            ++pass;
        }
        const int r = l + 1;
        for (int w = 0; w < 12; ++w) {
            const int c = w, tg = (w + r) % 12;
            col[c] ^= col[tg];
            row[tg] ^= row[c];
        }
    }
    for (int w = 0; w < 12; ++w) tb.zrow[w] = row[w];
    return tb;
}

__constant__ Tab GT = make_tab();

// pass-ordered Rot coefs: [pass*32 + lev*8 + j]; layer-0 at [480 + w*8 + j].
__device__ float g_coef[576];

__device__ __forceinline__ void rot8(const float* __restrict__ wp, float* o) {
    const float phi = wp[0], th = wp[1], om = wp[2];
    const float hs = 0.5f * (phi + om), hd = 0.5f * (phi - om), ht = 0.5f * th;
    const float ctt = cosf(ht), stt = sinf(ht);
    const float cs = cosf(hs), ss = sinf(hs);
    const float cd = cosf(hd), sd = sinf(hd);
    o[0] = cs * ctt;  o[1] = -ss * ctt;   // u00
    o[2] = -cd * stt; o[3] = -sd * stt;   // u01
    o[4] = cd * stt;  o[5] = -sd * stt;   // u10
    o[6] = cs * ctt;  o[7] = ss * ctt;    // u11
}

__global__ void rot_coef_kernel(const float* __restrict__ weights) {
    const int i = blockIdx.x * blockDim.x + threadIdx.x;
    if (i < 60) {
        const int ps = i >> 2, lev = i & 3;
        const int g = GT.ggate[ps][lev];
        float o[8];
        rot8(weights + g * 3, o);
        #pragma unroll
        for (int j = 0; j < 8; ++j) g_coef[ps * 32 + lev * 8 + j] = o[j];
    } else if (i >= 64 && i < 76) {
        const int w = i - 64;
        float o[8];
        rot8(weights + w * 3, o);
        #pragma unroll
        for (int j = 0; j < 8; ++j) g_coef[480 + w * 8 + j] = o[j];
    }
}

__device__ __forceinline__ v2f cmulv(v2f A, v2f B) {
    return (v2f){ A.x * B.x - A.y * B.y, A.x * B.y + A.y * B.x };
}

// packed complex butterfly: X' = A(.)x + B(.)y ; Y' = C(.)x + D(.)y
// via X' = Ar*x + Ai*xs + Br*y + Bi*ys, xs = (-x.y, x.x) -> v_pk_fma_f32
__device__ __forceinline__ void bf(v2f& X, v2f& Y,
                                   float Ar, float Ai, float Br, float Bi,
                                   float Cr, float Ci, float Dr, float Di) {
    const v2f x = X, y = Y;
    const v2f xs = { -x.y, x.x };
    const v2f ys = { -y.y, y.x };
    v2f nx = x * (v2f){ Ar, Ar };
    nx = __builtin_elementwise_fma((v2f){ Ai, Ai }, xs, nx);
    nx = __builtin_elementwise_fma((v2f){ Br, Br }, y,  nx);
    nx = __builtin_elementwise_fma((v2f){ Bi, Bi }, ys, nx);
    v2f ny = x * (v2f){ Cr, Cr };
    ny = __builtin_elementwise_fma((v2f){ Ci, Ci }, xs, ny);
    ny = __builtin_elementwise_fma((v2f){ Dr, Dr }, y,  ny);
    ny = __builtin_elementwise_fma((v2f){ Di, Di }, ys, ny);
    X = nx; Y = ny;
}

// ---------------------------------------------------------------------------
// One block (256 threads) per batch element. LDS = exactly the 32 KB state.
// 15 fused passes; 16-amp coset in NAMED v2f registers; Gray-code rolling
// addresses + opaque asm (R5/R7 lessons); packed fp32 math (R11).
// ---------------------------------------------------------------------------
__global__ __launch_bounds__(256) void qvl_fused(
    const float* __restrict__ v,        // (B, 512)
    const float* __restrict__ Wc,       // (12, 512)
    const float* __restrict__ bc,       // (12,)
    float* __restrict__ out)            // (B, 12)
{
    __shared__ v2f st[4096];     // 32768 B total LDS
    float* redf = reinterpret_cast<float*>(st);   // overlay (48 floats)

    const int t    = threadIdx.x;
    const int lane = t & 63;
    const int wv   = t >> 6;
    const int b    = blockIdx.x;

    // ---- x_w = tanh(v[b] . Wc[w] + bc[w]) * pi (partials into overlay) -----
    {
        const float2 vv = reinterpret_cast<const float2*>(v + b * 512)[t];
        #pragma unroll
        for (int w = 0; w < 12; ++w) {
            const float2 ww = reinterpret_cast<const float2*>(Wc + w * 512)[t];
            float p = vv.x * ww.x + vv.y * ww.y;
            #pragma unroll
            for (int s = 1; s < 64; s <<= 1) p += __shfl_xor(p, s, 64);
            if (lane == 0) redf[w * 4 + wv] = p;
        }
    }
    __syncthreads();

    // ---- per-wave: lanes 0..11 fold RY(x_w) + layer-0 Rot into (aw, bw) ----
    float awx = 0.0f, awy = 0.0f, bwx = 0.0f, bwy = 0.0f;
    if (lane < 12) {
        const float x = tanhf(redf[lane * 4 + 0] + redf[lane * 4 + 1] +
                              redf[lane * 4 + 2] + redf[lane * 4 + 3] + bc[lane]) * PI_F;
        const float h = 0.5f * x;
        const float c = cosf(h), s = sinf(h);
        const float* c8 = g_coef + 480 + lane * 8;
        awx = c8[0] * c + c8[2] * s;  awy = c8[1] * c + c8[3] * s;
        bwx = c8[4] * c + c8[6] * s;  bwy = c8[5] * c + c8[7] * s;
    }
    __syncthreads();   // overlay reads done before init overwrites st

    // ---- init: product state; p = k*256 + t (t bits -> wires 11..4) --------
    {
        v2f hi = { 1.0f, 0.0f };
        #pragma unroll
        for (int j = 0; j < 8; ++j) {
            const int src = 11 - j;            // wire for p bit j
            const float ax = __shfl(awx, src, 64), ay = __shfl(awy, src, 64);
            const float bx = __shfl(bwx, src, 64), by = __shfl(bwy, src, 64);
            const int bit = (t >> j) & 1;
            hi = cmulv(hi, (v2f){ bit ? bx : ax, bit ? by : ay });
        }
        v2f A3 = { __shfl(awx, 3, 64), __shfl(awy, 3, 64) };
        v2f B3 = { __shfl(bwx, 3, 64), __shfl(bwy, 3, 64) };
        v2f A2 = { __shfl(awx, 2, 64), __shfl(awy, 2, 64) };
        v2f B2 = { __shfl(bwx, 2, 64), __shfl(bwy, 2, 64) };
        v2f A1 = { __shfl(awx, 1, 64), __shfl(awy, 1, 64) };
        v2f B1 = { __shfl(bwx, 1, 64), __shfl(bwy, 1, 64) };
        v2f A0 = { __shfl(awx, 0, 64), __shfl(awy, 0, 64) };
        v2f B0 = { __shfl(bwx, 0, 64), __shfl(bwy, 0, 64) };
        v2f fA[4], fB[4];
        #pragma unroll
        for (int m = 0; m < 4; ++m) {
            fA[m] = cmulv((m & 1) ? B3 : A3, (m & 2) ? B2 : A2);   // p bits 8,9
            fB[m] = cmulv((m & 1) ? B1 : A1, (m & 2) ? B0 : A0);   // p bits 10,11
        }
        #pragma unroll
        for (int k = 0; k < 16; ++k)
            st[k * 256 + t] = cmulv(hi, cmulv(fA[k & 3], fB[k >> 2]));
    }

    // ---- 15 fused passes (layers 1..5, 4 gates each) ------------------------
    #pragma unroll 1
    for (int ps = 0; ps < 15; ++ps) {
        __syncthreads();
        const float* cp = g_coef + ps * 32;    // uniform -> s_load
        const unsigned m0 = GT.gmask[ps][0], m1 = GT.gmask[ps][1];
        const unsigned m2 = GT.gmask[ps][2], m3 = GT.gmask[ps][3];
        // null-space representative for this thread's coset
        unsigned q = 0u;
        #pragma unroll
        for (int i = 0; i < 8; ++i)
            q ^= (t & (1 << i)) ? GT.nb[ps][i] : 0u;

        // Gray-code load chain (one rolling address register)
        unsigned ad = q;
        v2f g0  = st[ad]; ad ^= m0;
        v2f g1  = st[ad]; ad ^= m1;
        v2f g3  = st[ad]; ad ^= m0;
        v2f g2  = st[ad]; ad ^= m2;
        v2f g6  = st[ad]; ad ^= m0;
        v2f g7  = st[ad]; ad ^= m1;
        v2f g5  = st[ad]; ad ^= m0;
        v2f g4  = st[ad]; ad ^= m3;
        v2f g12 = st[ad]; ad ^= m0;
        v2f g13 = st[ad]; ad ^= m1;
        v2f g15 = st[ad]; ad ^= m0;
        v2f g14 = st[ad]; ad ^= m2;
        v2f g10 = st[ad]; ad ^= m0;
        v2f g11 = st[ad]; ad ^= m1;
        v2f g9  = st[ad]; ad ^= m0;
        v2f g8  = st[ad];

        // all representatives have role parity 0 at every level -> raw coefs
        #define BF(X, Y) bf(X, Y, Ar, Ai, Br, Bi, Cr, Ci, Dr, Di)
        { const float Ar = cp[0],  Ai = cp[1],  Br = cp[2],  Bi = cp[3];
          const float Cr = cp[4],  Ci = cp[5],  Dr = cp[6],  Di = cp[7];
          BF(g0,g1); BF(g2,g3); BF(g4,g5); BF(g6,g7);
          BF(g8,g9); BF(g10,g11); BF(g12,g13); BF(g14,g15); }
        { const float Ar = cp[8],  Ai = cp[9],  Br = cp[10], Bi = cp[11];
          const float Cr = cp[12], Ci = cp[13], Dr = cp[14], Di = cp[15];
          BF(g0,g2); BF(g1,g3); BF(g4,g6); BF(g5,g7);
          BF(g8,g10); BF(g9,g11); BF(g12,g14); BF(g13,g15); }
        { const float Ar = cp[16], Ai = cp[17], Br = cp[18], Bi = cp[19];
          const float Cr = cp[20], Ci = cp[21], Dr = cp[22], Di = cp[23];
          BF(g0,g4); BF(g1,g5); BF(g2,g6); BF(g3,g7);
          BF(g8,g12); BF(g9,g13); BF(g10,g14); BF(g11,g15); }
        { const float Ar = cp[24], Ai = cp[25], Br = cp[26], Bi = cp[27];
          const float Cr = cp[28], Ci = cp[29], Dr = cp[30], Di = cp[31];
          BF(g0,g8); BF(g1,g9); BF(g2,g10); BF(g3,g11);
          BF(g4,g12); BF(g5,g13); BF(g6,g14); BF(g7,g15); }
        #undef BF

        // opaque barrier on q: store chain recomputed, not CSE'd with loads
        asm volatile("" : "+v"(q));

        ad = q;
        st[ad] = g0;  ad ^= m0;
        st[ad] = g1;  ad ^= m1;
        st[ad] = g3;  ad ^= m0;
        st[ad] = g2;  ad ^= m2;
        st[ad] = g6;  ad ^= m0;
        st[ad] = g7;  ad ^= m1;
        st[ad] = g5;  ad ^= m0;
        st[ad] = g4;  ad ^= m3;
        st[ad] = g12; ad ^= m0;
        st[ad] = g13; ad ^= m1;
        st[ad] = g15; ad ^= m0;
        st[ad] = g14; ad ^= m2;
        st[ad] = g10; ad ^= m0;
        st[ad] = g11; ad ^= m1;
        st[ad] = g9;  ad ^= m0;
        st[ad] = g8;
    }
    __syncthreads();

    // ---- PauliZ expvals; p = k*256 + t, sign = parity(p & zrow) ------------
    float p2[16];
    #pragma unroll
    for (int k = 0; k < 16; ++k) {
        const v2f aa = st[k * 256 + t];
        p2[k] = aa.x * aa.x + aa.y * aa.y;
    }
    __syncthreads();   // all st reads done before overlay reuse
    #pragma unroll
    for (int w = 0; w < 12; ++w) {
        const unsigned zr = GT.zrow[w];
        const unsigned Aw = (unsigned)__popc((unsigned)t & zr) & 1u;
        const unsigned nm = (zr >> 8) & 0xFu;
        unsigned P = 0u;
        P ^= (nm & 1u) ? 0xAAAAu : 0u;
        P ^= (nm & 2u) ? 0xCCCCu : 0u;
        P ^= (nm & 4u) ? 0xF0F0u : 0u;
        P ^= (nm & 8u) ? 0xFF00u : 0u;
        P ^= Aw ? 0xFFFFu : 0u;
        float z = 0.0f;
        #pragma unroll
        for (int k = 0; k < 16; ++k)
            z += ((P >> k) & 1u) ? -p2[k] : p2[k];
        #pragma unroll
        for (int s = 1; s < 64; s <<= 1) z += __shfl_xor(z, s, 64);
        if (lane == 0) redf[w * 4 + wv] = z;
    }
    __syncthreads();
    if (t < 12)
        out[b * 12 + t] = redf[t * 4 + 0] + redf[t * 4 + 1] +
                          redf[t * 4 + 2] + redf[t * 4 + 3];
}

extern "C" void kernel_launch(void* const* d_in, const int* in_sizes, int n_in,
                              void* d_out, int out_size, void* d_ws, size_t ws_size,
                              hipStream_t stream) {
    (void)n_in; (void)out_size; (void)d_ws; (void)ws_size;
    const float* v   = (const float*)d_in[0];
    const float* Wc  = (const float*)d_in[1];
    const float* bc  = (const float*)d_in[2];
    const float* wts = (const float*)d_in[3];
    float* out = (float*)d_out;

    const int B = in_sizes[0] / 512;
    rot_coef_kernel<<<1, 128, 0, stream>>>(wts);
    qvl_fused<<<B, 256, 0, stream>>>(v, Wc, bc, out);
}